// Round 5
// baseline (269.519 us; speedup 1.0000x reference)
//
#include <hip/hip_runtime.h>
#include <hip/hip_bf16.h>

typedef __attribute__((ext_vector_type(8))) __bf16 bf16x8;
typedef __attribute__((ext_vector_type(4))) __bf16 bf16x4;
typedef __attribute__((ext_vector_type(4))) float f32x4;

constexpr int M = 16384;
constexpr int K = 512;
constexpr int BK = 32;

__device__ __forceinline__ void async_copy16(const void* gsrc, void* ldst) {
  __builtin_amdgcn_global_load_lds(
      (const __attribute__((address_space(1))) unsigned int*)(gsrc),
      (__attribute__((address_space(3))) unsigned int*)(ldst),
      16, 0, 0);
}

// fast activations: v_exp_f32 + v_rcp_f32. Correct saturation at +/-inf.
__device__ __forceinline__ float frcp(float x) { return __builtin_amdgcn_rcpf(x); }
__device__ __forceinline__ float ftanh(float x) {
  return 1.0f - 2.0f * frcp(1.0f + __expf(2.0f * x));
}
__device__ __forceinline__ float fsigm(float x) {
  return frcp(1.0f + __expf(-x));
}

// ---------------------------------------------------------------------------
// GEMM: out[j] = act( A[j] (MxK) * W[j]^T (512xK) + b[j] ), bf16 out.
// 128x128 tile, BK=32, 4 waves 2x2 (64x64 each), 16x16x32 bf16 MFMA.
//
// R4 analysis: K-loop was LDS-BW-bound (32 KB LDS read per block-iter = 250
// cyc vs 78 cyc MFMA -> MfmaUtil ceiling ~30%, measured 20-25%). Fix: B (the
// weight, 512 KB/net, L2-hot across 128 m-blocks) is loaded DIRECTLY from
// global to registers (global_load_dwordx4: lanes fr x kc cover 16 rows x
// 64 B = full sectors), prefetched one K-iter ahead so L2 latency overlaps
// the MFMA phase. Only A goes through LDS (ping-pong, 1 barrier/iter).
// LDS read/iter halves -> ceiling ~60% MfmaUtil.
//
// Epilogue: whole-tile padded LDS scratch ([128][136]) -> one barrier pair,
// 8x bf16x8 fully-coalesced global stores.
// LAYER1 act: tanh. LAYER2: sigmoid(tanh(.)); net j==2 (z): tanh(sigmoid(tanh)).
// NOTE: never partially-unroll loops indexing acc[] (R2: scratch spill).
// ---------------------------------------------------------------------------
template <int LAYER>
__global__ __launch_bounds__(256) void gemm_kernel(
    const __bf16* __restrict__ A,     // LAYER1: hx [M][512]; LAYER2: a1 [3][M][512]
    const __bf16* __restrict__ W,     // [3][512][512] (N,K) row-major
    const float* __restrict__ bias,   // [7][512] fp32, use k=2j+1
    __bf16* __restrict__ out)         // [3][M][512] bf16
{
  const int j = blockIdx.z;
  const int mbase = blockIdx.x * 128;
  const int nbase = blockIdx.y * 128;
  const __bf16* Aj = (LAYER == 2) ? (A + (size_t)j * M * K) : A;
  const __bf16* Wj = W + (size_t)j * K * K;

  // A dbuf: 2 x 4096 el (16 KB). epilogue scratch: 128 x 136 el (34 KB).
  __shared__ __align__(16) __bf16 smem[17408];

  const int tid  = threadIdx.x;
  const int wid  = tid >> 6;
  const int lane = tid & 63;
  const int wm   = (wid >> 1) * 64;
  const int wn   = (wid & 1) * 64;
  const int srow = wid * 16 + (lane >> 2);
  const int scol = ((lane & 3) ^ ((lane >> 3) & 3)) * 8;  // swizzled src chunk
  const int fr   = lane & 15;
  const int kc   = lane >> 4;
  const int sw   = (fr >> 1) & 3;
  const int rowq = kc * 4;

  // A-only staging: 128 rows x 32 k, 256 thr x 16 B x 2 rounds.
  auto stage = [&](int p, int k0) {
    __bf16* As = smem + p * 4096;
#pragma unroll
    for (int r = 0; r < 2; ++r)
      async_copy16(Aj + (size_t)(mbase + r * 64 + srow) * K + (k0 + scol),
                   (void*)&As[(r * 64 + wid * 16) * BK]);
  };

  // B fragment straight from global (L2-hot): B[n=fr][k=kc*8..+8].
  const __bf16* Wbase = Wj + (size_t)(nbase + wn + fr) * K + kc * 8;
  auto loadB = [&](int k0, bf16x8* b) {
#pragma unroll
    for (int i = 0; i < 4; ++i)
      b[i] = *(const bf16x8*)&Wbase[(size_t)i * 16 * K + k0];
  };

  f32x4 acc[4][4] = {};

  stage(0, 0);
  bf16x8 bfr[4];
  loadB(0, bfr);

  int p = 0;
  for (int k0 = 0; k0 < K; k0 += BK) {
    __syncthreads();  // drains stage(p) + this wave's B loads (needed now)
    if (k0 + BK < K) stage(p ^ 1, k0 + BK);  // in flight during MFMA below

    bf16x8 bnext[4];
    if (k0 + BK < K) loadB(k0 + BK, bnext);  // L2 latency overlaps MFMA

    const __bf16* As = smem + p * 4096;
    bf16x8 af[4];
#pragma unroll
    for (int i = 0; i < 4; ++i)
      af[i] = *(const bf16x8*)&As[(wm + i * 16 + fr) * BK + ((kc ^ sw) * 8)];

#pragma unroll
    for (int mi = 0; mi < 4; ++mi)
#pragma unroll
      for (int ni = 0; ni < 4; ++ni)
        acc[mi][ni] = __builtin_amdgcn_mfma_f32_16x16x32_bf16(
            af[mi], bfr[ni], acc[mi][ni], 0, 0, 0);

#pragma unroll
    for (int i = 0; i < 4; ++i) bfr[i] = bnext[i];
    p ^= 1;
  }

  // Epilogue. C/D layout: col=fr, row=rowq+r.
  float bv[4];
  const float* bj = bias + (2 * j + 1) * 512 + nbase + wn;
#pragma unroll
  for (int ni = 0; ni < 4; ++ni) bv[ni] = bj[ni * 16 + fr];

  __syncthreads();  // all A frag reads done; smem reusable as C scratch
#pragma unroll
  for (int mi = 0; mi < 4; ++mi)
#pragma unroll
    for (int ni = 0; ni < 4; ++ni)
#pragma unroll
      for (int r = 0; r < 4; ++r) {
        float v = acc[mi][ni][r] + bv[ni];
        float res;
        if constexpr (LAYER == 1) {
          res = ftanh(v);
        } else {
          res = (j == 2) ? ftanh(fsigm(ftanh(v))) : fsigm(ftanh(v));
        }
        smem[(wm + mi * 16 + rowq + r) * 136 + (wn + ni * 16 + fr)] =
            (__bf16)res;
      }
  __syncthreads();
#pragma unroll
  for (int it = 0; it < 8; ++it) {
    const int s = it * 256 + tid;   // 0..2047
    const int row = s >> 4, ch = s & 15;
    bf16x8 v = *(const bf16x8*)&smem[row * 136 + ch * 8];
    *(bf16x8*)&out[(size_t)j * M * 512 + (size_t)(mbase + row) * 512 +
                   (nbase + ch * 8)] = v;
  }
}

// cy2 = f2*cx2 + i2*z    gates = [i2 | f2 | z] bf16 [3][M][512]
__global__ __launch_bounds__(256) void final_kernel(
    const __bf16* __restrict__ gates, const float* __restrict__ cx2,
    float* __restrict__ out)
{
  constexpr size_t NH = (size_t)M * 512;
  const size_t i = ((size_t)blockIdx.x * 256 + threadIdx.x) * 8;
  bf16x8 i2 = *(const bf16x8*)&gates[i];
  bf16x8 f2 = *(const bf16x8*)&gates[NH + i];
  bf16x8 zz = *(const bf16x8*)&gates[2 * NH + i];
  f32x4 c0 = *(const f32x4*)&cx2[i];
  f32x4 c1 = *(const f32x4*)&cx2[i + 4];
#pragma unroll
  for (int h = 0; h < 2; ++h) {
    f32x4 r;
#pragma unroll
    for (int q = 0; q < 4; ++q) {
      const int e = h * 4 + q;
      r[q] = (float)f2[e] * (h ? c1[q] : c0[q]) + (float)i2[e] * (float)zz[e];
    }
    *(f32x4*)&out[i + h * 4] = r;
  }
}

// one kernel for all fp32->bf16 conversions (hx, W1-sel, W2-sel): fewer
// launches. blocks [0,8192): hx; [8192,8960): W1; [8960,9728): W2.
__global__ __launch_bounds__(256) void cvt_all(
    const float* __restrict__ hx, const float* __restrict__ W1,
    const float* __restrict__ W2, __bf16* __restrict__ hxb,
    __bf16* __restrict__ W1b, __bf16* __restrict__ W2b)
{
  const int b = blockIdx.x;
  const float* src;
  __bf16* dst;
  size_t i;
  if (b < 8192) {
    src = hx; dst = hxb;
    i = ((size_t)b * 256 + threadIdx.x) * 4;
  } else {
    const int bb = (b < 8960) ? (b - 8192) : (b - 8960);
    const int jj = bb >> 8;              // 0..2
    const int blk = bb & 255;
    const size_t off = (size_t)(2 * jj + 1) * 262144;
    const size_t doff = (size_t)jj * 262144;
    i = ((size_t)blk * 256 + threadIdx.x) * 4;
    if (b < 8960) { src = W1 + off; dst = W1b + doff; }
    else          { src = W2 + off; dst = W2b + doff; }
  }
  f32x4 v = *(const f32x4*)&src[i];
  *(bf16x4*)&dst[i] = __builtin_convertvector(v, bf16x4);
}

extern "C" void kernel_launch(void* const* d_in, const int* in_sizes, int n_in,
                              void* d_out, int out_size, void* d_ws, size_t ws_size,
                              hipStream_t stream) {
  const float* hx  = (const float*)d_in[0];
  // d_in[1] = cx1 (dead: cy1 is never returned)
  const float* cx2 = (const float*)d_in[2];
  const float* W1  = (const float*)d_in[3];
  const float* b1  = (const float*)d_in[4];
  const float* W2  = (const float*)d_in[5];
  const float* b2  = (const float*)d_in[6];
  float* out = (float*)d_out;

  char* ws = (char*)d_ws;
  // hxb @0 (16 MB) | W1b @16777216 | W2b @18350080 | a1 @19922944 (50 MB)
  // gates @70254592 (50 MB) -> total ~121 MB
  __bf16* hxb   = (__bf16*)(ws);
  __bf16* W1b   = (__bf16*)(ws + 16777216);
  __bf16* W2b   = (__bf16*)(ws + 18350080);
  __bf16* a1    = (__bf16*)(ws + 19922944);
  __bf16* gates = (__bf16*)(ws + 70254592);

  cvt_all<<<9728, 256, 0, stream>>>(hx, W1, W2, hxb, W1b, W2b);

  gemm_kernel<1><<<dim3(128, 4, 3), 256, 0, stream>>>(hxb, W1b, b1, a1);
  gemm_kernel<2><<<dim3(128, 4, 3), 256, 0, stream>>>(a1, W2b, b2, gates);

  final_kernel<<<4096, 256, 0, stream>>>(gates, cx2, out);
}